// Round 9
// baseline (619.862 us; speedup 1.0000x reference)
//
#include <hip/hip_runtime.h>

// KronLinear fused kernel for MI355X (gfx950), v2.1 (latency-hiding; nt-store fix).
// out[n, a2*64+b2] = bias[a2*64+b2]
//   + sum_{r,a1,b1} x[n, a1*64+b1] * B[b2&3, b1, r*16+(b2>>2)] * A[r, a1, a2]
// Stage 1: T(64x256) = X(64x64) @ Bq(64x256), wave w owns c = r*64 + b2 with
//          b2 in [16w,16w+16) for ALL r (ct = 4*ci + w)  -> T slice is
//          wave-private, stage1->stage2 needs no barrier.
// Stage 2: out^T[b2, a2] = sum_k T''[k,b2] * A''[k,a2], K=256, per-wave.
// 4 tiles per block, register prefetch of next X tile hides HBM latency.

typedef __attribute__((ext_vector_type(8))) short bf16x8;
typedef __attribute__((ext_vector_type(4))) float f32x4;

__device__ __forceinline__ unsigned short f2bf(float f) {
    unsigned int u = __builtin_bit_cast(unsigned int, f);
    unsigned int r = u + 0x7fffu + ((u >> 16) & 1u);   // round-to-nearest-even
    return (unsigned short)(r >> 16);
}

// ---------------------------------------------------------------------------
// Prep: pack Bq (stage-1 B-operand) and A'' (stage-2 B-operand) into
// MFMA-fragment-ordered bf16 tables in workspace.
//   ws[0      .. 16384) : Bq_frag[ct=16][ks=2][lane=64][e=8]
//   ws[16384  .. 32768) : A_frag [at=4 ][ks=8][lane=64][e=8]
// B-operand convention (16x16x32): value = M[k = ks*32+(l>>4)*8+e][col = ct*16+(l&15)]
// ---------------------------------------------------------------------------
__global__ __launch_bounds__(256) void kron_prep(const float* __restrict__ A,
                                                 const float* __restrict__ B,
                                                 unsigned short* __restrict__ ws)
{
    int f = blockIdx.x * 256 + threadIdx.x;   // 0 .. 32768
    if (f < 16384) {
        int e = f & 7, l = (f >> 3) & 63, ks = (f >> 9) & 1, ct = f >> 10;
        int b1 = ks * 32 + (l >> 4) * 8 + e;          // stage-1 K = b1
        int c  = ct * 16 + (l & 15);                  // c = r*64 + b2
        int bb = c & 63, rr = c >> 6;
        float v = B[(bb & 3) * 4096 + b1 * 64 + (rr * 16 + (bb >> 2))];
        ws[f] = f2bf(v);
    } else {
        int f2 = f - 16384;
        int e = f2 & 7, l = (f2 >> 3) & 63, ks = (f2 >> 9) & 7, at = f2 >> 12;
        int k = ks * 32 + (l >> 4) * 8 + e;           // k = r*64 + a1
        int rr = k >> 6, a1 = k & 63;
        int a2 = at * 16 + (l & 15);
        float v = A[rr * 4096 + a1 * 64 + a2];
        ws[16384 + f2] = f2bf(v);
    }
}

#define TPB_TILES 4

// ---------------------------------------------------------------------------
// LDS: Xs = bf16 X tile [a1=64][b1=64], XOR-swizzled rows (8 KB)
//      Tw = per-wave T slice [wave][b2'=16][k=256] bf16, swizzled (4 x 8 KB)
// Swizzle: byte_off_in_row ^= (row&7)<<4  (keeps 8/16B groups intact)
// ---------------------------------------------------------------------------
__global__ __launch_bounds__(256, 4) void kron_main(const float* __restrict__ x,
                                                    const float* __restrict__ bias,
                                                    const unsigned short* __restrict__ ws,
                                                    float* __restrict__ out)
{
    __shared__ unsigned short Xs[64 * 64];        // 8 KB
    __shared__ unsigned short Tw[4 * 16 * 256];   // 32 KB, wave-private 8 KB slices

    const int t  = threadIdx.x;
    const int w  = t >> 6;       // wave 0..3
    const int l  = t & 63;       // lane
    const int lr = l & 15;
    const int lg = l >> 4;

    const unsigned short* __restrict__ Bq = ws;            // [ct][ks][lane][8]
    const unsigned short* __restrict__ Af = ws + 16384;    // [at][ks8][lane][8]

    const size_t tile0 = (size_t)blockIdx.x * TPB_TILES;

    // ---- prologue: prefetch X(tile0) into registers ----
    f32x4 pf[4];
    {
        const float* __restrict__ xp = x + tile0 * 4096;
        #pragma unroll
        for (int it = 0; it < 4; ++it)
            pf[it] = *reinterpret_cast<const f32x4*>(xp + it * 1024 + t * 4);
    }

    for (int tt = 0; tt < TPB_TILES; ++tt) {
        // ---- stage X(tt): regs -> bf16 swizzled LDS ----
        #pragma unroll
        for (int it = 0; it < 4; ++it) {
            int idx = it * 1024 + t * 4;
            int a1 = idx >> 6, b1 = idx & 63;
            f32x4 v = pf[it];
            unsigned int p0 = (unsigned int)f2bf(v[0]) | ((unsigned int)f2bf(v[1]) << 16);
            unsigned int p1 = (unsigned int)f2bf(v[2]) | ((unsigned int)f2bf(v[3]) << 16);
            int colb = (b1 * 2) ^ ((a1 & 7) << 4);
            *reinterpret_cast<uint2*>(reinterpret_cast<char*>(Xs) + a1 * 128 + colb) =
                make_uint2(p0, p1);
        }
        __syncthreads();   // B1: Xs ready

        // ---- stage 1 (two ci-halves to cap AGPR use) ----
        #pragma unroll
        for (int h = 0; h < 2; ++h) {
            f32x4 acc1[2][4];   // [cj][a1t]
            #pragma unroll
            for (int cj = 0; cj < 2; ++cj)
                #pragma unroll
                for (int a1t = 0; a1t < 4; ++a1t)
                    acc1[cj][a1t] = (f32x4){0.f, 0.f, 0.f, 0.f};

            #pragma unroll
            for (int ks = 0; ks < 2; ++ks) {
                bf16x8 bfr[2];
                #pragma unroll
                for (int cj = 0; cj < 2; ++cj) {
                    int ct = (2 * h + cj) * 4 + w;          // ct = 4*ci + w
                    bfr[cj] = *reinterpret_cast<const bf16x8*>(Bq + ((ct * 2 + ks) * 64 + l) * 8);
                }
                #pragma unroll
                for (int a1t = 0; a1t < 4; ++a1t) {
                    int row  = a1t * 16 + lr;
                    int colb = ((ks * 32 + lg * 8) * 2) ^ ((row & 7) << 4);
                    bf16x8 af = *reinterpret_cast<const bf16x8*>(
                        reinterpret_cast<const char*>(Xs) + row * 128 + colb);
                    acc1[0][a1t] = __builtin_amdgcn_mfma_f32_16x16x32_bf16(af, bfr[0], acc1[0][a1t], 0, 0, 0);
                    acc1[1][a1t] = __builtin_amdgcn_mfma_f32_16x16x32_bf16(af, bfr[1], acc1[1][a1t], 0, 0, 0);
                }
            }
            // write Tw slice: D[row=a1t*16+lg*4+e][col=lr] -> T[a1][c], r=ci, b2'=lr
            #pragma unroll
            for (int cj = 0; cj < 2; ++cj) {
                #pragma unroll
                for (int a1t = 0; a1t < 4; ++a1t) {
                    int ci = 2 * h + cj;
                    int k0 = ci * 64 + a1t * 16 + lg * 4;   // k = r*64 + a1
                    f32x4 d = acc1[cj][a1t];
                    unsigned int p0 = (unsigned int)f2bf(d[0]) | ((unsigned int)f2bf(d[1]) << 16);
                    unsigned int p1 = (unsigned int)f2bf(d[2]) | ((unsigned int)f2bf(d[3]) << 16);
                    int colb = (k0 * 2) ^ ((lr & 7) << 4);
                    *reinterpret_cast<uint2*>(reinterpret_cast<char*>(Tw)
                        + w * 8192 + lr * 512 + colb) = make_uint2(p0, p1);
                }
            }
        }
        __syncthreads();   // B2: all waves done reading Xs (safe to refill)

        // ---- prefetch X(tt+1): issued now, consumed after stage2+epilogue ----
        if (tt + 1 < TPB_TILES) {
            const float* __restrict__ xp = x + (tile0 + tt + 1) * 4096;
            #pragma unroll
            for (int it = 0; it < 4; ++it)
                pf[it] = *reinterpret_cast<const f32x4*>(xp + it * 1024 + t * 4);
        }

        // ---- stage 2: per-wave, K=256 over wave-private Tw slice ----
        f32x4 acc2[4];
        #pragma unroll
        for (int at = 0; at < 4; ++at) acc2[at] = (f32x4){0.f, 0.f, 0.f, 0.f};

        #pragma unroll
        for (int ks8 = 0; ks8 < 8; ++ks8) {
            int colb = (ks8 * 64 + lg * 16) ^ ((lr & 7) << 4);
            bf16x8 aop = *reinterpret_cast<const bf16x8*>(
                reinterpret_cast<const char*>(Tw) + w * 8192 + lr * 512 + colb);
            #pragma unroll
            for (int at = 0; at < 4; ++at) {
                bf16x8 bop = *reinterpret_cast<const bf16x8*>(Af + ((at * 8 + ks8) * 64 + l) * 8);
                acc2[at] = __builtin_amdgcn_mfma_f32_16x16x32_bf16(aop, bop, acc2[at], 0, 0, 0);
            }
        }

        // ---- epilogue: D row = b2' = lg*4+e -> b2 = 16w+lg*4+e; col = a2 = at*16+lr
        float* __restrict__ op = out + (tile0 + tt) * 4096;
        const int ob = 16 * w + lg * 4;
        #pragma unroll
        for (int at = 0; at < 4; ++at) {
            int idx = (at * 16 + lr) * 64 + ob;
            f32x4 bv = *reinterpret_cast<const f32x4*>(bias + idx);
            f32x4 d = acc2[at];
            f32x4 o = d + bv;
            __builtin_nontemporal_store(o, reinterpret_cast<f32x4*>(op + idx));
        }
    }
}

extern "C" void kernel_launch(void* const* d_in, const int* in_sizes, int n_in,
                              void* d_out, int out_size, void* d_ws, size_t ws_size,
                              hipStream_t stream) {
    const float* x    = (const float*)d_in[0];
    const float* A    = (const float*)d_in[1];
    const float* B    = (const float*)d_in[2];
    const float* bias = (const float*)d_in[3];
    float* out = (float*)d_out;
    unsigned short* ws = (unsigned short*)d_ws;

    kron_prep<<<128, 256, 0, stream>>>(A, B, ws);
    // 8192 tiles, 4 per block
    kron_main<<<8192 / TPB_TILES, 256, 0, stream>>>(x, bias, ws, out);
}

// Round 11
// 610.668 us; speedup vs baseline: 1.0151x; 1.0151x over previous
//
#include <hip/hip_runtime.h>

// KronLinear fused kernel for MI355X (gfx950), v2.2 (plain stores — nt-store
// caused 5x write amplification + RMW fetch; see Round-9 post-mortem).
// out[n, a2*64+b2] = bias[a2*64+b2]
//   + sum_{r,a1,b1} x[n, a1*64+b1] * B[b2&3, b1, r*16+(b2>>2)] * A[r, a1, a2]
// Stage 1: T(64x256) = X(64x64) @ Bq(64x256), wave w owns c = r*64 + b2 with
//          b2 in [16w,16w+16) for ALL r (ct = 4*ci + w)  -> T slice is
//          wave-private, stage1->stage2 needs no barrier.
// Stage 2: out^T[b2, a2] = sum_k T''[k,b2] * A''[k,a2], K=256, per-wave.
// 4 tiles per block, register prefetch of next X tile hides HBM latency.

typedef __attribute__((ext_vector_type(8))) short bf16x8;
typedef __attribute__((ext_vector_type(4))) float f32x4;

__device__ __forceinline__ unsigned short f2bf(float f) {
    unsigned int u = __builtin_bit_cast(unsigned int, f);
    unsigned int r = u + 0x7fffu + ((u >> 16) & 1u);   // round-to-nearest-even
    return (unsigned short)(r >> 16);
}

// ---------------------------------------------------------------------------
// Prep: pack Bq (stage-1 B-operand) and A'' (stage-2 B-operand) into
// MFMA-fragment-ordered bf16 tables in workspace.
//   ws[0      .. 16384) : Bq_frag[ct=16][ks=2][lane=64][e=8]
//   ws[16384  .. 32768) : A_frag [at=4 ][ks=8][lane=64][e=8]
// B-operand convention (16x16x32): value = M[k = ks*32+(l>>4)*8+e][col = ct*16+(l&15)]
// ---------------------------------------------------------------------------
__global__ __launch_bounds__(256) void kron_prep(const float* __restrict__ A,
                                                 const float* __restrict__ B,
                                                 unsigned short* __restrict__ ws)
{
    int f = blockIdx.x * 256 + threadIdx.x;   // 0 .. 32768
    if (f < 16384) {
        int e = f & 7, l = (f >> 3) & 63, ks = (f >> 9) & 1, ct = f >> 10;
        int b1 = ks * 32 + (l >> 4) * 8 + e;          // stage-1 K = b1
        int c  = ct * 16 + (l & 15);                  // c = r*64 + b2
        int bb = c & 63, rr = c >> 6;
        float v = B[(bb & 3) * 4096 + b1 * 64 + (rr * 16 + (bb >> 2))];
        ws[f] = f2bf(v);
    } else {
        int f2 = f - 16384;
        int e = f2 & 7, l = (f2 >> 3) & 63, ks = (f2 >> 9) & 7, at = f2 >> 12;
        int k = ks * 32 + (l >> 4) * 8 + e;           // k = r*64 + a1
        int rr = k >> 6, a1 = k & 63;
        int a2 = at * 16 + (l & 15);
        float v = A[rr * 4096 + a1 * 64 + a2];
        ws[16384 + f2] = f2bf(v);
    }
}

#define TPB_TILES 4

// ---------------------------------------------------------------------------
// LDS: Xs = bf16 X tile [a1=64][b1=64], XOR-swizzled rows (8 KB)
//      Tw = per-wave T slice [wave][b2'=16][k=256] bf16, swizzled (4 x 8 KB)
// Swizzle: byte_off_in_row ^= (row&7)<<4  (keeps 8/16B groups intact)
// ---------------------------------------------------------------------------
__global__ __launch_bounds__(256, 4) void kron_main(const float* __restrict__ x,
                                                    const float* __restrict__ bias,
                                                    const unsigned short* __restrict__ ws,
                                                    float* __restrict__ out)
{
    __shared__ unsigned short Xs[64 * 64];        // 8 KB
    __shared__ unsigned short Tw[4 * 16 * 256];   // 32 KB, wave-private 8 KB slices

    const int t  = threadIdx.x;
    const int w  = t >> 6;       // wave 0..3
    const int l  = t & 63;       // lane
    const int lr = l & 15;
    const int lg = l >> 4;

    const unsigned short* __restrict__ Bq = ws;            // [ct][ks][lane][8]
    const unsigned short* __restrict__ Af = ws + 16384;    // [at][ks8][lane][8]

    const size_t tile0 = (size_t)blockIdx.x * TPB_TILES;

    // ---- prologue: prefetch X(tile0) into registers ----
    f32x4 pf[4];
    {
        const float* __restrict__ xp = x + tile0 * 4096;
        #pragma unroll
        for (int it = 0; it < 4; ++it)
            pf[it] = *reinterpret_cast<const f32x4*>(xp + it * 1024 + t * 4);
    }

    for (int tt = 0; tt < TPB_TILES; ++tt) {
        // ---- stage X(tt): regs -> bf16 swizzled LDS ----
        #pragma unroll
        for (int it = 0; it < 4; ++it) {
            int idx = it * 1024 + t * 4;
            int a1 = idx >> 6, b1 = idx & 63;
            f32x4 v = pf[it];
            unsigned int p0 = (unsigned int)f2bf(v[0]) | ((unsigned int)f2bf(v[1]) << 16);
            unsigned int p1 = (unsigned int)f2bf(v[2]) | ((unsigned int)f2bf(v[3]) << 16);
            int colb = (b1 * 2) ^ ((a1 & 7) << 4);
            *reinterpret_cast<uint2*>(reinterpret_cast<char*>(Xs) + a1 * 128 + colb) =
                make_uint2(p0, p1);
        }
        __syncthreads();   // B1: Xs ready

        // ---- stage 1 (two ci-halves to cap AGPR use) ----
        #pragma unroll
        for (int h = 0; h < 2; ++h) {
            f32x4 acc1[2][4];   // [cj][a1t]
            #pragma unroll
            for (int cj = 0; cj < 2; ++cj)
                #pragma unroll
                for (int a1t = 0; a1t < 4; ++a1t)
                    acc1[cj][a1t] = (f32x4){0.f, 0.f, 0.f, 0.f};

            #pragma unroll
            for (int ks = 0; ks < 2; ++ks) {
                bf16x8 bfr[2];
                #pragma unroll
                for (int cj = 0; cj < 2; ++cj) {
                    int ct = (2 * h + cj) * 4 + w;          // ct = 4*ci + w
                    bfr[cj] = *reinterpret_cast<const bf16x8*>(Bq + ((ct * 2 + ks) * 64 + l) * 8);
                }
                #pragma unroll
                for (int a1t = 0; a1t < 4; ++a1t) {
                    int row  = a1t * 16 + lr;
                    int colb = ((ks * 32 + lg * 8) * 2) ^ ((row & 7) << 4);
                    bf16x8 af = *reinterpret_cast<const bf16x8*>(
                        reinterpret_cast<const char*>(Xs) + row * 128 + colb);
                    acc1[0][a1t] = __builtin_amdgcn_mfma_f32_16x16x32_bf16(af, bfr[0], acc1[0][a1t], 0, 0, 0);
                    acc1[1][a1t] = __builtin_amdgcn_mfma_f32_16x16x32_bf16(af, bfr[1], acc1[1][a1t], 0, 0, 0);
                }
            }
            // write Tw slice: D[row=a1t*16+lg*4+e][col=lr] -> T[a1][c], r=ci, b2'=lr
            #pragma unroll
            for (int cj = 0; cj < 2; ++cj) {
                #pragma unroll
                for (int a1t = 0; a1t < 4; ++a1t) {
                    int ci = 2 * h + cj;
                    int k0 = ci * 64 + a1t * 16 + lg * 4;   // k = r*64 + a1
                    f32x4 d = acc1[cj][a1t];
                    unsigned int p0 = (unsigned int)f2bf(d[0]) | ((unsigned int)f2bf(d[1]) << 16);
                    unsigned int p1 = (unsigned int)f2bf(d[2]) | ((unsigned int)f2bf(d[3]) << 16);
                    int colb = (k0 * 2) ^ ((lr & 7) << 4);
                    *reinterpret_cast<uint2*>(reinterpret_cast<char*>(Tw)
                        + w * 8192 + lr * 512 + colb) = make_uint2(p0, p1);
                }
            }
        }
        __syncthreads();   // B2: all waves done reading Xs (safe to refill)

        // ---- prefetch X(tt+1): issued now, consumed after stage2+epilogue ----
        if (tt + 1 < TPB_TILES) {
            const float* __restrict__ xp = x + (tile0 + tt + 1) * 4096;
            #pragma unroll
            for (int it = 0; it < 4; ++it)
                pf[it] = *reinterpret_cast<const f32x4*>(xp + it * 1024 + t * 4);
        }

        // ---- stage 2: per-wave, K=256 over wave-private Tw slice ----
        f32x4 acc2[4];
        #pragma unroll
        for (int at = 0; at < 4; ++at) acc2[at] = (f32x4){0.f, 0.f, 0.f, 0.f};

        #pragma unroll
        for (int ks8 = 0; ks8 < 8; ++ks8) {
            int colb = (ks8 * 64 + lg * 16) ^ ((lr & 7) << 4);
            bf16x8 aop = *reinterpret_cast<const bf16x8*>(
                reinterpret_cast<const char*>(Tw) + w * 8192 + lr * 512 + colb);
            #pragma unroll
            for (int at = 0; at < 4; ++at) {
                bf16x8 bop = *reinterpret_cast<const bf16x8*>(Af + ((at * 8 + ks8) * 64 + l) * 8);
                acc2[at] = __builtin_amdgcn_mfma_f32_16x16x32_bf16(aop, bop, acc2[at], 0, 0, 0);
            }
        }

        // ---- epilogue: D row = b2' = lg*4+e -> b2 = 16w+lg*4+e; col = a2 = at*16+lr
        // PLAIN stores (L2 write-combining) — nt-stores amplified writes 5x.
        float* __restrict__ op = out + (tile0 + tt) * 4096;
        const int ob = 16 * w + lg * 4;
        #pragma unroll
        for (int at = 0; at < 4; ++at) {
            int idx = (at * 16 + lr) * 64 + ob;
            f32x4 bv = *reinterpret_cast<const f32x4*>(bias + idx);
            f32x4 d = acc2[at];
            *reinterpret_cast<f32x4*>(op + idx) = d + bv;
        }
    }
}

extern "C" void kernel_launch(void* const* d_in, const int* in_sizes, int n_in,
                              void* d_out, int out_size, void* d_ws, size_t ws_size,
                              hipStream_t stream) {
    const float* x    = (const float*)d_in[0];
    const float* A    = (const float*)d_in[1];
    const float* B    = (const float*)d_in[2];
    const float* bias = (const float*)d_in[3];
    float* out = (float*)d_out;
    unsigned short* ws = (unsigned short*)d_ws;

    kron_prep<<<128, 256, 0, stream>>>(A, B, ws);
    // 8192 tiles, 4 per block
    kron_main<<<8192 / TPB_TILES, 256, 0, stream>>>(x, bias, ws, out);
}

// Round 12
// 399.789 us; speedup vs baseline: 1.5505x; 1.5275x over previous
//
#include <hip/hip_runtime.h>

// KronLinear fused kernel for MI355X (gfx950), v2.3.
// Round-11 fix: __launch_bounds__(256,4) capped total regs at 128; with 48
// accumulator AGPRs the 16-VGPR prefetch array spilled to scratch ->
// ~1.3 GB of amplified scratch traffic (FETCH 652 MB / WRITE 625 MB).
// Relaxed to (256,2) so the prefetch stays in registers.
// out[n, a2*64+b2] = bias[a2*64+b2]
//   + sum_{r,a1,b1} x[n, a1*64+b1] * B[b2&3, b1, r*16+(b2>>2)] * A[r, a1, a2]
// Stage 1: T(64x256) = X(64x64) @ Bq(64x256), wave w owns c = r*64 + b2 with
//          b2 in [16w,16w+16) for ALL r (ct = 4*ci + w)  -> T slice is
//          wave-private, stage1->stage2 needs no barrier.
// Stage 2: out^T[b2, a2] = sum_k T''[k,b2] * A''[k,a2], K=256, per-wave.
// 4 tiles per block, register prefetch of next X tile hides HBM latency.

typedef __attribute__((ext_vector_type(8))) short bf16x8;
typedef __attribute__((ext_vector_type(4))) float f32x4;

__device__ __forceinline__ unsigned short f2bf(float f) {
    unsigned int u = __builtin_bit_cast(unsigned int, f);
    unsigned int r = u + 0x7fffu + ((u >> 16) & 1u);   // round-to-nearest-even
    return (unsigned short)(r >> 16);
}

// ---------------------------------------------------------------------------
// Prep: pack Bq (stage-1 B-operand) and A'' (stage-2 B-operand) into
// MFMA-fragment-ordered bf16 tables in workspace.
//   ws[0      .. 16384) : Bq_frag[ct=16][ks=2][lane=64][e=8]
//   ws[16384  .. 32768) : A_frag [at=4 ][ks=8][lane=64][e=8]
// B-operand convention (16x16x32): value = M[k = ks*32+(l>>4)*8+e][col = ct*16+(l&15)]
// ---------------------------------------------------------------------------
__global__ __launch_bounds__(256) void kron_prep(const float* __restrict__ A,
                                                 const float* __restrict__ B,
                                                 unsigned short* __restrict__ ws)
{
    int f = blockIdx.x * 256 + threadIdx.x;   // 0 .. 32768
    if (f < 16384) {
        int e = f & 7, l = (f >> 3) & 63, ks = (f >> 9) & 1, ct = f >> 10;
        int b1 = ks * 32 + (l >> 4) * 8 + e;          // stage-1 K = b1
        int c  = ct * 16 + (l & 15);                  // c = r*64 + b2
        int bb = c & 63, rr = c >> 6;
        float v = B[(bb & 3) * 4096 + b1 * 64 + (rr * 16 + (bb >> 2))];
        ws[f] = f2bf(v);
    } else {
        int f2 = f - 16384;
        int e = f2 & 7, l = (f2 >> 3) & 63, ks = (f2 >> 9) & 7, at = f2 >> 12;
        int k = ks * 32 + (l >> 4) * 8 + e;           // k = r*64 + a1
        int rr = k >> 6, a1 = k & 63;
        int a2 = at * 16 + (l & 15);
        float v = A[rr * 4096 + a1 * 64 + a2];
        ws[16384 + f2] = f2bf(v);
    }
}

#define TPB_TILES 4

// ---------------------------------------------------------------------------
// LDS: Xs = bf16 X tile [a1=64][b1=64], XOR-swizzled rows (8 KB)
//      Tw = per-wave T slice [wave][b2'=16][k=256] bf16, swizzled (4 x 8 KB)
// Swizzle: byte_off_in_row ^= (row&7)<<4  (keeps 8/16B groups intact)
// ---------------------------------------------------------------------------
__global__ __launch_bounds__(256, 2) void kron_main(const float* __restrict__ x,
                                                    const float* __restrict__ bias,
                                                    const unsigned short* __restrict__ ws,
                                                    float* __restrict__ out)
{
    __shared__ unsigned short Xs[64 * 64];        // 8 KB
    __shared__ unsigned short Tw[4 * 16 * 256];   // 32 KB, wave-private 8 KB slices

    const int t  = threadIdx.x;
    const int w  = t >> 6;       // wave 0..3
    const int l  = t & 63;       // lane
    const int lr = l & 15;
    const int lg = l >> 4;

    const unsigned short* __restrict__ Bq = ws;            // [ct][ks][lane][8]
    const unsigned short* __restrict__ Af = ws + 16384;    // [at][ks8][lane][8]

    const size_t tile0 = (size_t)blockIdx.x * TPB_TILES;

    // ---- prologue: prefetch X(tile0) into registers ----
    f32x4 pf[4];
    {
        const float* __restrict__ xp = x + tile0 * 4096;
        #pragma unroll
        for (int it = 0; it < 4; ++it)
            pf[it] = *reinterpret_cast<const f32x4*>(xp + it * 1024 + t * 4);
    }

    for (int tt = 0; tt < TPB_TILES; ++tt) {
        // ---- stage X(tt): regs -> bf16 swizzled LDS ----
        #pragma unroll
        for (int it = 0; it < 4; ++it) {
            int idx = it * 1024 + t * 4;
            int a1 = idx >> 6, b1 = idx & 63;
            f32x4 v = pf[it];
            unsigned int p0 = (unsigned int)f2bf(v[0]) | ((unsigned int)f2bf(v[1]) << 16);
            unsigned int p1 = (unsigned int)f2bf(v[2]) | ((unsigned int)f2bf(v[3]) << 16);
            int colb = (b1 * 2) ^ ((a1 & 7) << 4);
            *reinterpret_cast<uint2*>(reinterpret_cast<char*>(Xs) + a1 * 128 + colb) =
                make_uint2(p0, p1);
        }
        __syncthreads();   // B1: Xs ready

        // ---- stage 1 (two ci-halves to cap AGPR use) ----
        #pragma unroll
        for (int h = 0; h < 2; ++h) {
            f32x4 acc1[2][4];   // [cj][a1t]
            #pragma unroll
            for (int cj = 0; cj < 2; ++cj)
                #pragma unroll
                for (int a1t = 0; a1t < 4; ++a1t)
                    acc1[cj][a1t] = (f32x4){0.f, 0.f, 0.f, 0.f};

            #pragma unroll
            for (int ks = 0; ks < 2; ++ks) {
                bf16x8 bfr[2];
                #pragma unroll
                for (int cj = 0; cj < 2; ++cj) {
                    int ct = (2 * h + cj) * 4 + w;          // ct = 4*ci + w
                    bfr[cj] = *reinterpret_cast<const bf16x8*>(Bq + ((ct * 2 + ks) * 64 + l) * 8);
                }
                #pragma unroll
                for (int a1t = 0; a1t < 4; ++a1t) {
                    int row  = a1t * 16 + lr;
                    int colb = ((ks * 32 + lg * 8) * 2) ^ ((row & 7) << 4);
                    bf16x8 af = *reinterpret_cast<const bf16x8*>(
                        reinterpret_cast<const char*>(Xs) + row * 128 + colb);
                    acc1[0][a1t] = __builtin_amdgcn_mfma_f32_16x16x32_bf16(af, bfr[0], acc1[0][a1t], 0, 0, 0);
                    acc1[1][a1t] = __builtin_amdgcn_mfma_f32_16x16x32_bf16(af, bfr[1], acc1[1][a1t], 0, 0, 0);
                }
            }
            // write Tw slice: D[row=a1t*16+lg*4+e][col=lr] -> T[a1][c], r=ci, b2'=lr
            #pragma unroll
            for (int cj = 0; cj < 2; ++cj) {
                #pragma unroll
                for (int a1t = 0; a1t < 4; ++a1t) {
                    int ci = 2 * h + cj;
                    int k0 = ci * 64 + a1t * 16 + lg * 4;   // k = r*64 + a1
                    f32x4 d = acc1[cj][a1t];
                    unsigned int p0 = (unsigned int)f2bf(d[0]) | ((unsigned int)f2bf(d[1]) << 16);
                    unsigned int p1 = (unsigned int)f2bf(d[2]) | ((unsigned int)f2bf(d[3]) << 16);
                    int colb = (k0 * 2) ^ ((lr & 7) << 4);
                    *reinterpret_cast<uint2*>(reinterpret_cast<char*>(Tw)
                        + w * 8192 + lr * 512 + colb) = make_uint2(p0, p1);
                }
            }
        }
        __syncthreads();   // B2: all waves done reading Xs (safe to refill)

        // ---- prefetch X(tt+1): issued now, consumed after stage2+epilogue ----
        if (tt + 1 < TPB_TILES) {
            const float* __restrict__ xp = x + (tile0 + tt + 1) * 4096;
            #pragma unroll
            for (int it = 0; it < 4; ++it)
                pf[it] = *reinterpret_cast<const f32x4*>(xp + it * 1024 + t * 4);
        }

        // ---- stage 2: per-wave, K=256 over wave-private Tw slice ----
        f32x4 acc2[4];
        #pragma unroll
        for (int at = 0; at < 4; ++at) acc2[at] = (f32x4){0.f, 0.f, 0.f, 0.f};

        #pragma unroll
        for (int ks8 = 0; ks8 < 8; ++ks8) {
            int colb = (ks8 * 64 + lg * 16) ^ ((lr & 7) << 4);
            bf16x8 aop = *reinterpret_cast<const bf16x8*>(
                reinterpret_cast<const char*>(Tw) + w * 8192 + lr * 512 + colb);
            #pragma unroll
            for (int at = 0; at < 4; ++at) {
                bf16x8 bop = *reinterpret_cast<const bf16x8*>(Af + ((at * 8 + ks8) * 64 + l) * 8);
                acc2[at] = __builtin_amdgcn_mfma_f32_16x16x32_bf16(aop, bop, acc2[at], 0, 0, 0);
            }
        }

        // ---- epilogue: D row = b2' = lg*4+e -> b2 = 16w+lg*4+e; col = a2 = at*16+lr
        // Plain stores: one wave store instr covers 16 full 64B lines.
        float* __restrict__ op = out + (tile0 + tt) * 4096;
        const int ob = 16 * w + lg * 4;
        #pragma unroll
        for (int at = 0; at < 4; ++at) {
            int idx = (at * 16 + lr) * 64 + ob;
            f32x4 bv = *reinterpret_cast<const f32x4*>(bias + idx);
            f32x4 d = acc2[at];
            *reinterpret_cast<f32x4*>(op + idx) = d + bv;
        }
    }
}

extern "C" void kernel_launch(void* const* d_in, const int* in_sizes, int n_in,
                              void* d_out, int out_size, void* d_ws, size_t ws_size,
                              hipStream_t stream) {
    const float* x    = (const float*)d_in[0];
    const float* A    = (const float*)d_in[1];
    const float* B    = (const float*)d_in[2];
    const float* bias = (const float*)d_in[3];
    float* out = (float*)d_out;
    unsigned short* ws = (unsigned short*)d_ws;

    kron_prep<<<128, 256, 0, stream>>>(A, B, ws);
    // 8192 tiles, 4 per block
    kron_main<<<8192 / TPB_TILES, 256, 0, stream>>>(x, bias, ws, out);
}